// Round 21
// baseline (542.376 us; speedup 1.0000x reference)
//
#include <hip/hip_runtime.h>
#include <cstdint>
#include <cstddef>

typedef unsigned short ushort_t;
typedef short s16x8 __attribute__((ext_vector_type(8)));
typedef float f32x4 __attribute__((ext_vector_type(4)));
typedef unsigned u32x4 __attribute__((ext_vector_type(4)));

#define MFMA(A,B,C) __builtin_amdgcn_mfma_f32_16x16x32_bf16((A),(B),(C),0,0,0)

__device__ __forceinline__ float b2f(ushort_t h){ return __uint_as_float(((unsigned)h)<<16); }
__device__ __forceinline__ ushort_t f2b(float f){
  unsigned u = __float_as_uint(f);
  u += 0x7FFFu + ((u >> 16) & 1u);
  return (ushort_t)(u >> 16);
}
// monotone float<->uint encoding for atomic min/max
__device__ __forceinline__ unsigned f2o(float f){
  unsigned u = __float_as_uint(f);
  return (u & 0x80000000u) ? ~u : (u | 0x80000000u);
}
__device__ __forceinline__ float o2f(unsigned u){
  unsigned b = (u & 0x80000000u) ? (u & 0x7FFFFFFFu) : ~u;
  return __uint_as_float(b);
}

struct QT { const float* w[10]; ushort_t* o[10]; int n[10]; float os[10]; int pm[10]; };

__global__ void init_k(unsigned* slots){
  int t = threadIdx.x;
  if (t < 20) slots[t] = (t & 1) ? 0u : 0xFFFFFFFFu;
}

__global__ __launch_bounds__(256) void minmax_k(QT qt, unsigned* slots){
  int t = blockIdx.y;
  const float4* w = (const float4*)qt.w[t];
  int n4 = qt.n[t] >> 2;
  float mn = 3.4e38f, mx = -3.4e38f;
  for (int i = blockIdx.x*256 + threadIdx.x; i < n4; i += gridDim.x*256){
    float4 v = w[i];
    mn = fminf(mn, fminf(fminf(v.x, v.y), fminf(v.z, v.w)));
    mx = fmaxf(mx, fmaxf(fmaxf(v.x, v.y), fmaxf(v.z, v.w)));
  }
  #pragma unroll
  for (int o = 1; o < 64; o <<= 1){
    mn = fminf(mn, __shfl_xor(mn, o));
    mx = fmaxf(mx, __shfl_xor(mx, o));
  }
  __shared__ float smn[4], smx[4];
  int wv = threadIdx.x >> 6;
  if ((threadIdx.x & 63) == 0){ smn[wv] = mn; smx[wv] = mx; }
  __syncthreads();
  if (threadIdx.x == 0){
    mn = fminf(fminf(smn[0], smn[1]), fminf(smn[2], smn[3]));
    mx = fmaxf(fmaxf(smx[0], smx[1]), fmaxf(smx[2], smx[3]));
    atomicMin(&slots[2*t], f2o(mn));
    atomicMax(&slots[2*t+1], f2o(mx));
  }
}

// dequant with optional hidden/gate 32-row interleave (pm=1).
__global__ __launch_bounds__(256) void dequant_k(QT qt, const unsigned* __restrict__ slots){
  int t = blockIdx.y;
  float mn = o2f(slots[2*t]), mx = o2f(slots[2*t+1]);
  float delta = (mx - mn) * (1.f/255.f);
  float zp = rintf(-mn / delta);
  float osc = qt.os[t];
  int pm = qt.pm[t];
  const float4* w = (const float4*)qt.w[t];
  ushort4* o = (ushort4*)qt.o[t];
  int n4 = qt.n[t] >> 2;
  for (int i = blockIdx.x*256 + threadIdx.x; i < n4; i += gridDim.x*256){
    float4 v = w[i];
    ushort4 r;
    float q;
    q = fminf(fmaxf(rintf(v.x/delta) + zp, 0.f), 255.f); r.x = f2b((q - zp)*delta*osc);
    q = fminf(fmaxf(rintf(v.y/delta) + zp, 0.f), 255.f); r.y = f2b((q - zp)*delta*osc);
    q = fminf(fmaxf(rintf(v.z/delta) + zp, 0.f), 255.f); r.z = f2b((q - zp)*delta*osc);
    q = fminf(fmaxf(rintf(v.w/delta) + zp, 0.f), 255.f); r.w = f2b((q - zp)*delta*osc);
    size_t oi = i;
    if (pm){
      int row = i >> 8, c4 = i & 255;
      int nr = (row < 4096) ? ((row >> 5) << 6) + (row & 31)
                            : (((row - 4096) >> 5) << 6) + 32 + ((row - 4096) & 31);
      oi = (size_t)nr*256 + c4;
    }
    o[oi] = r;
  }
}

__global__ __launch_bounds__(256) void f2b_k(const float* __restrict__ in, ushort_t* __restrict__ out, int n4){
  for (int i = blockIdx.x*256 + threadIdx.x; i < n4; i += gridDim.x*256){
    float4 v = ((const float4*)in)[i];
    ushort4 r; r.x = f2b(v.x); r.y = f2b(v.y); r.z = f2b(v.z); r.w = f2b(v.w);
    ((ushort4*)out)[i] = r;
  }
}

// LayerNorm over rows of 1024 f32 -> bf16. One block per row.
__global__ __launch_bounds__(256) void ln_k(const float* __restrict__ x, const float* __restrict__ g,
                                            const float* __restrict__ b, ushort_t* __restrict__ out){
  int row = blockIdx.x, tid = threadIdx.x;
  float4 v = ((const float4*)(x + (size_t)row*1024))[tid];
  float s  = v.x + v.y + v.z + v.w;
  float s2 = v.x*v.x + v.y*v.y + v.z*v.z + v.w*v.w;
  #pragma unroll
  for (int o = 1; o < 64; o <<= 1){ s += __shfl_xor(s, o); s2 += __shfl_xor(s2, o); }
  __shared__ float rs[4], rs2[4];
  int wv = tid >> 6;
  if ((tid & 63) == 0){ rs[wv] = s; rs2[wv] = s2; }
  __syncthreads();
  s = rs[0]+rs[1]+rs[2]+rs[3]; s2 = rs2[0]+rs2[1]+rs2[2]+rs2[3];
  float mu = s * (1.f/1024.f);
  float var = s2 * (1.f/1024.f) - mu*mu;
  float rstd = rsqrtf(var + 1e-5f);
  float4 gv = ((const float4*)g)[tid], bv = ((const float4*)b)[tid];
  ushort4 r;
  r.x = f2b((v.x - mu)*rstd*gv.x + bv.x);
  r.y = f2b((v.y - mu)*rstd*gv.y + bv.y);
  r.z = f2b((v.z - mu)*rstd*gv.z + bv.z);
  r.w = f2b((v.w - mu)*rstd*gv.w + bv.w);
  ((ushort4*)(out + (size_t)row*1024))[tid] = r;
}

// Fused: x = p0+p1+p2+p3+bias+resid (write f32), then LayerNorm(x)*g+b -> bf16. One block per row.
__global__ __launch_bounds__(256) void reduce4_ln_k(
    const float* __restrict__ p0, const float* __restrict__ p1,
    const float* __restrict__ p2, const float* __restrict__ p3,
    const float* __restrict__ bias, const float* __restrict__ resid,
    const float* __restrict__ lng, const float* __restrict__ lnb_,
    float* __restrict__ xout, ushort_t* __restrict__ lnout)
{
  int row = blockIdx.x, tid = threadIdx.x;
  size_t bi = (size_t)row*256 + tid;
  float4 a = ((const float4*)p0)[bi];
  float4 b = ((const float4*)p1)[bi];
  float4 c = ((const float4*)p2)[bi];
  float4 d = ((const float4*)p3)[bi];
  float4 r = ((const float4*)resid)[bi];
  float4 bb = ((const float4*)bias)[tid];
  float4 v;
  v.x = (a.x + b.x) + (c.x + d.x) + r.x + bb.x;
  v.y = (a.y + b.y) + (c.y + d.y) + r.y + bb.y;
  v.z = (a.z + b.z) + (c.z + d.z) + r.z + bb.z;
  v.w = (a.w + b.w) + (c.w + d.w) + r.w + bb.w;
  ((float4*)xout)[bi] = v;
  float s  = v.x + v.y + v.z + v.w;
  float s2 = v.x*v.x + v.y*v.y + v.z*v.z + v.w*v.w;
  #pragma unroll
  for (int o = 1; o < 64; o <<= 1){ s += __shfl_xor(s, o); s2 += __shfl_xor(s2, o); }
  __shared__ float rs[4], rs2[4];
  int wv = tid >> 6;
  if ((tid & 63) == 0){ rs[wv] = s; rs2[wv] = s2; }
  __syncthreads();
  s = rs[0]+rs[1]+rs[2]+rs[3]; s2 = rs2[0]+rs2[1]+rs2[2]+rs2[3];
  float mu = s * (1.f/1024.f);
  float var = s2 * (1.f/1024.f) - mu*mu;
  float rstd = rsqrtf(var + 1e-5f);
  float4 gv = ((const float4*)lng)[tid], bv = ((const float4*)lnb_)[tid];
  ushort4 o;
  o.x = f2b((v.x - mu)*rstd*gv.x + bv.x);
  o.y = f2b((v.y - mu)*rstd*gv.y + bv.y);
  o.z = f2b((v.z - mu)*rstd*gv.z + bv.z);
  o.w = f2b((v.w - mu)*rstd*gv.w + bv.w);
  ((ushort4*)(lnout + (size_t)row*1024))[tid] = o;
}

// C[M,N] = A[M,K_total] @ W[N,K_total]^T (+bias)(+resid). 256x128 tile, BK=32,
// 8 waves (4Mx2N). 3-deep ring + counted vmcnt across raw s_barrier (T4).
__global__ __launch_bounds__(512) void gemm_k(
    const ushort_t* __restrict__ A, const ushort_t* __restrict__ W,
    const float* __restrict__ bias, const float* __restrict__ resid,
    float* __restrict__ outF, ushort_t* __restrict__ outB,
    int M, int N, int K, int lda, int ldw)
{
  __shared__ ushort_t As[3][256*32];
  __shared__ ushort_t Bs[3][128*32];
  const int tid = threadIdx.x;
  const int lane = tid & 63, wv = tid >> 6;
  const int g = lane >> 4, qi = lane & 15;

  const int gx = gridDim.x, gy = gridDim.y;
  const int lid = blockIdx.x + blockIdx.y * gx;
  int m0, n0;
  if (((gx & 3) | (gy & 1)) == 0){
    const int w = gx >> 2, h = gy >> 1;
    const int xcd = lid & 7, o = lid >> 3;
    const int cx = xcd & 3, cy = xcd >> 2;
    n0 = (cx * w + (o % w)) * 128;
    m0 = (cy * h + (o / w)) * 256;
  } else {
    n0 = blockIdx.x * 128;
    m0 = blockIdx.y * 256;
  }

  const int koff = blockIdx.z * K;
  if (gridDim.z > 1) outF += (size_t)blockIdx.z * M * N;

  const int wr = (wv >> 1) * 64, wc = (wv & 1) * 64;
  f32x4 acc[4][4] = {};

  const int ra0 = tid >> 2,        sa0 = (tid & 3) ^ ((ra0 >> 1) & 3);
  const int ra1 = (512+tid) >> 2,  sa1 = ((512+tid) & 3) ^ ((ra1 >> 1) & 3);
  const int aA0 = (m0 + ra0 < M) ? m0 + ra0 : M - 1;
  const int aA1 = (m0 + ra1 < M) ? m0 + ra1 : M - 1;
  const size_t dA0 = (size_t)tid*8, dA1 = (size_t)(512+tid)*8, dB0 = (size_t)tid*8;

  #define GSTAGE(bi_, kt_) do {                                                    \
    __builtin_amdgcn_global_load_lds(                                              \
      (const __attribute__((address_space(1))) void*)(A + (size_t)aA0*lda + koff + (kt_) + sa0*8), \
      (__attribute__((address_space(3))) void*)(&As[bi_][dA0]), 16, 0, 0);         \
    __builtin_amdgcn_global_load_lds(                                              \
      (const __attribute__((address_space(1))) void*)(A + (size_t)aA1*lda + koff + (kt_) + sa1*8), \
      (__attribute__((address_space(3))) void*)(&As[bi_][dA1]), 16, 0, 0);         \
    __builtin_amdgcn_global_load_lds(                                              \
      (const __attribute__((address_space(1))) void*)(W + (size_t)(n0 + ra0)*ldw + koff + (kt_) + sa0*8), \
      (__attribute__((address_space(3))) void*)(&Bs[bi_][dB0]), 16, 0, 0);         \
  } while(0)

  const int nt = K >> 5;
  GSTAGE(0, 0);
  if (nt > 1) GSTAGE(1, 32);
  if (nt > 1) asm volatile("s_waitcnt vmcnt(3)" ::: "memory");
  else        asm volatile("s_waitcnt vmcnt(0)" ::: "memory");
  __builtin_amdgcn_s_barrier();
  __builtin_amdgcn_sched_barrier(0);

  int bi = 0;
  for (int t = 0; t < nt; ++t){
    int b2 = bi + 2; if (b2 >= 3) b2 -= 3;
    if (t + 2 < nt) GSTAGE(b2, (t + 2) << 5);
    s16x8 af[4], bfr[4];
    #pragma unroll
    for (int mi = 0; mi < 4; ++mi){
      int row = wr + mi*16 + qi;
      int sl = g ^ ((row >> 1) & 3);
      af[mi] = *(const s16x8*)(&As[bi][row*32 + sl*8]);
    }
    #pragma unroll
    for (int ni = 0; ni < 4; ++ni){
      int row = wc + ni*16 + qi;
      int sl = g ^ ((row >> 1) & 3);
      bfr[ni] = *(const s16x8*)(&Bs[bi][row*32 + sl*8]);
    }
    __builtin_amdgcn_s_setprio(1);
    #pragma unroll
    for (int mi = 0; mi < 4; ++mi)
      #pragma unroll
      for (int ni = 0; ni < 4; ++ni)
        acc[mi][ni] = MFMA(af[mi], bfr[ni], acc[mi][ni]);
    __builtin_amdgcn_s_setprio(0);
    if (t + 1 < nt){
      if (t + 2 < nt) asm volatile("s_waitcnt vmcnt(3)" ::: "memory");
      else            asm volatile("s_waitcnt vmcnt(0)" ::: "memory");
      __builtin_amdgcn_s_barrier();
      __builtin_amdgcn_sched_barrier(0);
    }
    bi += 1; if (bi >= 3) bi -= 3;
  }
  #undef GSTAGE

  #pragma unroll
  for (int mi = 0; mi < 4; ++mi){
    #pragma unroll
    for (int r = 0; r < 4; ++r){
      int row = m0 + wr + mi*16 + g*4 + r;
      if (row >= M) continue;
      #pragma unroll
      for (int ni = 0; ni < 4; ++ni){
        int col = n0 + wc + ni*16 + qi;
        float v = acc[mi][ni][r];
        if (bias)  v += bias[col];
        if (resid) v += resid[(size_t)row*N + col];
        if (outF)  outF[(size_t)row*N + col] = v;
        else       outB[(size_t)row*N + col] = f2b(v);
      }
    }
  }
}

// ff1 + fused GEGLU, register-only epilogue (32-row interleaved Wp; dequant pm=1).
__global__ __launch_bounds__(512) void gemm_ff1_k(
    const ushort_t* __restrict__ A, const ushort_t* __restrict__ W,
    const float* __restrict__ biasHG, ushort_t* __restrict__ out)
{
  __shared__ ushort_t As[3][256*32];
  __shared__ ushort_t Bs[3][128*32];
  const int tid = threadIdx.x;
  const int lane = tid & 63, wv = tid >> 6;
  const int g = lane >> 4, qi = lane & 15;
  const int lda = 1024, ldw = 1024;

  const int gx = gridDim.x;   // 64
  const int gy = gridDim.y;   // 16
  const int lid = blockIdx.x + blockIdx.y * gx;
  const int w = gx >> 2, h = gy >> 1;
  const int xcd = lid & 7, o = lid >> 3;
  const int cx = xcd & 3, cy = xcd >> 2;
  const int n0 = (cx * w + (o % w)) * 128;
  const int m0 = (cy * h + (o / w)) * 256;

  const int wr = (wv >> 1) * 64, wc = (wv & 1) * 64;
  f32x4 acc[4][4] = {};

  const int ra0 = tid >> 2,        sa0 = (tid & 3) ^ ((ra0 >> 1) & 3);
  const int ra1 = (512+tid) >> 2,  sa1 = ((512+tid) & 3) ^ ((ra1 >> 1) & 3);
  const int aA0 = m0 + ra0, aA1 = m0 + ra1;
  const size_t dA0 = (size_t)tid*8, dA1 = (size_t)(512+tid)*8, dB0 = (size_t)tid*8;

  #define GSTAGEF(bi_, kt_) do {                                                   \
    __builtin_amdgcn_global_load_lds(                                              \
      (const __attribute__((address_space(1))) void*)(A + (size_t)aA0*lda + (kt_) + sa0*8), \
      (__attribute__((address_space(3))) void*)(&As[bi_][dA0]), 16, 0, 0);         \
    __builtin_amdgcn_global_load_lds(                                              \
      (const __attribute__((address_space(1))) void*)(A + (size_t)aA1*lda + (kt_) + sa1*8), \
      (__attribute__((address_space(3))) void*)(&As[bi_][dA1]), 16, 0, 0);         \
    __builtin_amdgcn_global_load_lds(                                              \
      (const __attribute__((address_space(1))) void*)(W + (size_t)(n0 + ra0)*ldw + (kt_) + sa0*8), \
      (__attribute__((address_space(3))) void*)(&Bs[bi_][dB0]), 16, 0, 0);         \
  } while(0)

  const int nt = 1024 >> 5;
  GSTAGEF(0, 0);
  GSTAGEF(1, 32);
  asm volatile("s_waitcnt vmcnt(3)" ::: "memory");
  __builtin_amdgcn_s_barrier();
  __builtin_amdgcn_sched_barrier(0);

  int bi = 0;
  for (int t = 0; t < nt; ++t){
    int b2 = bi + 2; if (b2 >= 3) b2 -= 3;
    if (t + 2 < nt) GSTAGEF(b2, (t + 2) << 5);
    s16x8 af[4], bfr[4];
    #pragma unroll
    for (int mi = 0; mi < 4; ++mi){
      int row = wr + mi*16 + qi;
      int sl = g ^ ((row >> 1) & 3);
      af[mi] = *(const s16x8*)(&As[bi][row*32 + sl*8]);
    }
    #pragma unroll
    for (int ni = 0; ni < 4; ++ni){
      int row = wc + ni*16 + qi;
      int sl = g ^ ((row >> 1) & 3);
      bfr[ni] = *(const s16x8*)(&Bs[bi][row*32 + sl*8]);
    }
    __builtin_amdgcn_s_setprio(1);
    #pragma unroll
    for (int mi = 0; mi < 4; ++mi)
      #pragma unroll
      for (int ni = 0; ni < 4; ++ni)
        acc[mi][ni] = MFMA(af[mi], bfr[ni], acc[mi][ni]);
    __builtin_amdgcn_s_setprio(0);
    if (t + 1 < nt){
      if (t + 2 < nt) asm volatile("s_waitcnt vmcnt(3)" ::: "memory");
      else            asm volatile("s_waitcnt vmcnt(0)" ::: "memory");
      __builtin_amdgcn_s_barrier();
      __builtin_amdgcn_sched_barrier(0);
    }
    bi += 1; if (bi >= 3) bi -= 3;
  }
  #undef GSTAGEF

  const int jw = (n0 + wc) >> 1;
  #pragma unroll
  for (int mi = 0; mi < 4; ++mi){
    #pragma unroll
    for (int r = 0; r < 4; ++r){
      int row = m0 + wr + mi*16 + g*4 + r;
      #pragma unroll
      for (int ni = 0; ni < 2; ++ni){
        int j = jw + ni*16 + qi;
        float hv = acc[mi][ni][r]   + biasHG[j];
        float gg = acc[mi][ni+2][r] + biasHG[4096 + j];
        float tt = 0.7978845608f*(gg + 0.044715f*gg*gg*gg);
        float e  = __builtin_amdgcn_exp2f(2.885390082f*tt);   // e^(2t)
        float th = 1.f - 2.f/(e + 1.f);
        float ge = 0.5f*gg*(1.f + th);
        out[(size_t)row*4096 + j] = f2b(hv * ge);
      }
    }
  }
}

// out = p0+p1+p2+p3 (+bias) (+resid); outF f32 or outB bf16. Row width 1024 f32.
__global__ __launch_bounds__(256) void reduce4_k(const float* __restrict__ p0, const float* __restrict__ p1,
                                                 const float* __restrict__ p2, const float* __restrict__ p3,
                                                 const float* __restrict__ bias, const float* __restrict__ resid,
                                                 float* __restrict__ outF, ushort_t* __restrict__ outB, int n4){
  for (int i = blockIdx.x*256 + threadIdx.x; i < n4; i += gridDim.x*256){
    float4 a = ((const float4*)p0)[i];
    float4 b = ((const float4*)p1)[i];
    float4 c = ((const float4*)p2)[i];
    float4 d = ((const float4*)p3)[i];
    float4 v;
    v.x = (a.x + b.x) + (c.x + d.x);
    v.y = (a.y + b.y) + (c.y + d.y);
    v.z = (a.z + b.z) + (c.z + d.z);
    v.w = (a.w + b.w) + (c.w + d.w);
    if (bias){
      float4 bb = ((const float4*)bias)[i & 255];
      v.x += bb.x; v.y += bb.y; v.z += bb.z; v.w += bb.w;
    }
    if (resid){
      float4 r = ((const float4*)resid)[i];
      v.x += r.x; v.y += r.y; v.z += r.z; v.w += r.w;
    }
    if (outF) ((float4*)outF)[i] = v;
    else {
      ushort4 o; o.x = f2b(v.x); o.y = f2b(v.y); o.z = f2b(v.z); o.w = f2b(v.w);
      ((ushort4*)outB)[i] = o;
    }
  }
}

// Transpose V into Vt[b][h][64][nk_pad] (zero-padded). One block per (n-tile of 128, b*16+h).
__global__ __launch_bounds__(256) void vtrans_k(const ushort_t* __restrict__ src, ushort_t* __restrict__ dst,
                                                int rows, int stride, int col_off, int nk_pad){
  __shared__ ushort_t ldst[64*130];
  int n0 = blockIdx.x * 128;
  int b = blockIdx.y >> 4, h = blockIdx.y & 15;
  const ushort_t* s = src + (size_t)b*rows*stride + col_off + h*64;
  for (int idx = threadIdx.x; idx < 128*64; idx += 256){
    int n = idx >> 6, d = idx & 63;
    int ng = n0 + n;
    ushort_t v = (ng < rows) ? s[(size_t)ng*stride + d] : (ushort_t)0;
    ldst[d*130 + n] = v;
  }
  __syncthreads();
  ushort_t* o = dst + (size_t)(b*16 + h)*64*nk_pad;
  for (int idx = threadIdx.x; idx < 64*128; idx += 256){
    int d = idx >> 7, n = idx & 127;
    if (n0 + n < nk_pad) o[(size_t)d*nk_pad + n0 + n] = ldst[d*130 + n];
  }
}

// Flash attention, H=16, DH=64. Block = 8 waves; wave owns 16 q rows (128 q/block).
// KVBLK=32 staged in LDS (dbuf): waves 0-3 stage K, waves 4-7 stage V.
// Swapped QK^T (scale pre-folded, log2 domain); native v_exp; exact rescale-skip;
// deferred per-lane l; v_cvt_pk pack; setprio around MFMA clusters.
__global__ __launch_bounds__(512) void attn_k(
    const ushort_t* __restrict__ Q, const ushort_t* __restrict__ Kp, const ushort_t* __restrict__ Vt,
    ushort_t* __restrict__ O, int nq, int nk, int qstride, int kvstride, int nk_pad)
{
  __shared__ ushort_t Ks[2][32*64];   // [key 32][d 64], 8 slots/row, XOR row&7
  __shared__ ushort_t Vs[2][64*32];   // [d 64][key 32], 4 slots/row, XOR (row>>1)&3
  const int tid = threadIdx.x, lane = tid & 63, wv = tid >> 6;
  const int g = lane >> 4, qi = lane & 15;
  const int b = blockIdx.y >> 4, h = blockIdx.y & 15;
  const int q0 = blockIdx.x*128 + wv*16;

  const ushort_t* Qr = Q + (size_t)(b*nq + q0 + qi)*qstride + h*64;
  s16x8 qf0 = *(const s16x8*)(Qr + g*8);
  s16x8 qf1 = *(const s16x8*)(Qr + 32 + g*8);
  const ushort_t* Kb = Kp + (size_t)b*nk*kvstride + h*64;
  const ushort_t* Vb = Vt + (size_t)(b*16 + h)*64*nk_pad;

  const int krow = (wv & 3)*8 + (lane >> 3);
  const int kgsl = (lane & 7) ^ (krow & 7);
  const int vrow = (wv & 3)*16 + (lane >> 2);
  const int vgsl = (lane & 3) ^ ((vrow >> 1) & 3);

  #define STAGE(buf, kb_) do {                                                   \
    if (wv < 4){                                                                 \
      int kr_ = (kb_) + krow; if (kr_ >= nk) kr_ = nk - 1;                       \
      __builtin_amdgcn_global_load_lds(                                          \
        (const __attribute__((address_space(1))) void*)(Kb + (size_t)kr_*kvstride + kgsl*8), \
        (__attribute__((address_space(3))) void*)(&Ks[buf][(size_t)(wv&3)*512]), 16, 0, 0); \
    } else {                                                                     \
      __builtin_amdgcn_global_load_lds(                                          \
        (const __attribute__((address_space(1))) void*)(Vb + (size_t)vrow*nk_pad + (kb_) + vgsl*8), \
        (__attribute__((address_space(3))) void*)(&Vs[buf][(size_t)(wv&3)*512]), 16, 0, 0); \
    }                                                                            \
  } while(0)

  const int nkp = (nk + 31) & ~31;
  f32x4 ot[4] = {};
  float m_run = -1e30f, lsum = 0.f;

  const int ks0 = (g     ^ (qi & 7)) * 8;
  const int ks1 = ((4+g) ^ (qi & 7)) * 8;
  const int vs0 = (g ^ ((qi >> 1) & 3)) * 8;

  STAGE(0, 0);
  asm volatile("s_waitcnt vmcnt(0)" ::: "memory");
  __syncthreads();
  int cur = 0;
  for (int kb = 0; kb < nkp; kb += 32){
    if (kb + 32 < nkp) STAGE(cur^1, kb + 32);
    s16x8 ka0 = *(const s16x8*)(&Ks[cur][(qi)*64      + ks0]);
    s16x8 ka1 = *(const s16x8*)(&Ks[cur][(qi)*64      + ks1]);
    s16x8 kb0 = *(const s16x8*)(&Ks[cur][(16+qi)*64   + ks0]);
    s16x8 kb1 = *(const s16x8*)(&Ks[cur][(16+qi)*64   + ks1]);
    s16x8 vf0 = *(const s16x8*)(&Vs[cur][(qi)*32      + vs0]);
    s16x8 vf1 = *(const s16x8*)(&Vs[cur][(16+qi)*32   + vs0]);
    s16x8 vf2 = *(const s16x8*)(&Vs[cur][(32+qi)*32   + vs0]);
    s16x8 vf3 = *(const s16x8*)(&Vs[cur][(48+qi)*32   + vs0]);

    f32x4 st0 = {}, st1 = {};
    __builtin_amdgcn_s_setprio(1);
    st0 = MFMA(ka0, qf0, st0);
    st0 = MFMA(ka1, qf1, st0);
    st1 = MFMA(kb0, qf0, st1);
    st1 = MFMA(kb1, qf1, st1);
    __builtin_amdgcn_s_setprio(0);
    float s[8];
    #pragma unroll
    for (int r = 0; r < 4; ++r){ s[r] = st0[r]; s[4+r] = st1[r]; }   // scale pre-folded
    if (kb + 32 > nk){
      #pragma unroll
      for (int r = 0; r < 4; ++r){
        if (kb + 4*g + r >= nk)      s[r]   = -1e30f;
        if (kb + 16 + 4*g + r >= nk) s[4+r] = -1e30f;
      }
    }
    float m1 = fmaxf(fmaxf(s[0], s[1]), s[2]);
    float m2 = fmaxf(fmaxf(s[3], s[4]), s[5]);
    float bm = fmaxf(fmaxf(m1, m2), fmaxf(s[6], s[7]));
    bm = fmaxf(bm, __shfl_xor(bm, 16));
    bm = fmaxf(bm, __shfl_xor(bm, 32));
    if (!__all(bm <= m_run)){
      float m_new = fmaxf(m_run, bm);
      float fac = __builtin_amdgcn_exp2f(m_run - m_new);
      lsum *= fac;
      #pragma unroll
      for (int dd = 0; dd < 4; ++dd)
        #pragma unroll
        for (int r = 0; r < 4; ++r) ot[dd][r] *= fac;
      m_run = m_new;
    }
    float p[8], ps = 0.f;
    #pragma unroll
    for (int i = 0; i < 8; ++i){ p[i] = __builtin_amdgcn_exp2f(s[i] - m_run); ps += p[i]; }
    lsum += ps;
    unsigned pk[4];
    #pragma unroll
    for (int r = 0; r < 4; ++r)
      asm("v_cvt_pk_bf16_f32 %0, %1, %2" : "=v"(pk[r]) : "v"(p[r]), "v"(p[4+r]));
    int srcbase = ((2*g) & 3) * 16 + qi;
    unsigned sh0[4], sh1[4];
    #pragma unroll
    for (int r = 0; r < 4; ++r){
      sh0[r] = (unsigned)__shfl((int)pk[r], srcbase);
      sh1[r] = (unsigned)__shfl((int)pk[r], srcbase + 16);
    }
    unsigned sel = (g >> 1) ? 0x07060302u : 0x05040100u;
    u32x4 pw;
    pw[0] = __builtin_amdgcn_perm(sh0[1], sh0[0], sel);
    pw[1] = __builtin_amdgcn_perm(sh0[3], sh0[2], sel);
    pw[2] = __builtin_amdgcn_perm(sh1[1], sh1[0], sel);
    pw[3] = __builtin_amdgcn_perm(sh1[3], sh1[2], sel);
    s16x8 pf = __builtin_bit_cast(s16x8, pw);
    __builtin_amdgcn_s_setprio(1);
    ot[0] = MFMA(vf0, pf, ot[0]);
    ot[1] = MFMA(vf1, pf, ot[1]);
    ot[2] = MFMA(vf2, pf, ot[2]);
    ot[3] = MFMA(vf3, pf, ot[3]);
    __builtin_amdgcn_s_setprio(0);

    asm volatile("s_waitcnt vmcnt(0)" ::: "memory");
    __syncthreads();
    cur ^= 1;
  }
  #undef STAGE
  float l = lsum;
  l += __shfl_xor(l, 16);
  l += __shfl_xor(l, 32);
  float inv = 1.f / l;
  ushort_t* Or = O + (size_t)(b*nq + q0 + qi)*1024 + h*64;
  #pragma unroll
  for (int dd = 0; dd < 4; ++dd)
    #pragma unroll
    for (int r = 0; r < 4; ++r)
      Or[dd*16 + 4*g + r] = f2b(ot[dd][r] * inv);
}

extern "C" void kernel_launch(void* const* d_in, const int* in_sizes, int n_in,
                              void* d_out, int out_size, void* d_ws, size_t ws_size,
                              hipStream_t stream)
{
  const float* x    = (const float*)d_in[0];
  const float* ctx  = (const float*)d_in[1];
  const float* ln1g = (const float*)d_in[2];
  const float* ln1b = (const float*)d_in[3];
  const float* ln2g = (const float*)d_in[4];
  const float* ln2b = (const float*)d_in[5];
  const float* ln3g = (const float*)d_in[6];
  const float* ln3b = (const float*)d_in[7];
  const float* q1w  = (const float*)d_in[8];
  const float* k1w  = (const float*)d_in[9];
  const float* v1w  = (const float*)d_in[10];
  const float* o1w  = (const float*)d_in[11];
  const float* o1b  = (const float*)d_in[12];
  const float* q2w  = (const float*)d_in[13];
  const float* k2w  = (const float*)d_in[14];
  const float* v2w  = (const float*)d_in[15];
  const float* o2w  = (const float*)d_in[16];
  const float* o2b  = (const float*)d_in[17];
  const float* ff1w = (const float*)d_in[18];
  const float* ff1b = (const float*)d_in[19];
  const float* ff2w = (const float*)d_in[20];
  const float* ff2b = (const float*)d_in[21];

  char* base = (char*)d_ws;
  size_t off = 0;
  auto alloc = [&](size_t bytes) -> char* {
    char* p = base + off;
    off += (bytes + 255) & ~(size_t)255;
    return p;
  };
  unsigned*  slots = (unsigned*)alloc(80);
  ushort_t*  ctxb  = (ushort_t*)alloc((size_t)154*768*2);
  ushort_t*  wqkv1 = (ushort_t*)alloc((size_t)3072*1024*2);
  ushort_t*  o1d   = (ushort_t*)alloc((size_t)1024*1024*2);
  ushort_t*  q2d   = (ushort_t*)alloc((size_t)1024*1024*2);
  ushort_t*  wkv2  = (ushort_t*)alloc((size_t)2048*768*2);
  ushort_t*  o2d   = (ushort_t*)alloc((size_t)1024*1024*2);
  ushort_t*  f1d   = (ushort_t*)alloc((size_t)8192*1024*2);
  ushort_t*  f2d   = (ushort_t*)alloc((size_t)1024*4096*2);
  ushort_t*  lnb   = (ushort_t*)alloc((size_t)4096*1024*2);
  ushort_t*  qkvb  = (ushort_t*)alloc((size_t)4096*3072*2);
  ushort_t*  q2b   = (ushort_t*)alloc((size_t)4096*1024*2);
  ushort_t*  atb   = (ushort_t*)alloc((size_t)4096*1024*2);
  ushort_t*  kvb   = (ushort_t*)alloc((size_t)154*2048*2);
  ushort_t*  vt1   = (ushort_t*)alloc((size_t)2*16*64*2048*2);
  ushort_t*  vt2   = (ushort_t*)alloc((size_t)2*16*64*96*2);
  float*     x1    = (float*)alloc((size_t)4096*1024*4);
  float*     x2    = (float*)alloc((size_t)4096*1024*4);
  ushort_t*  hb    = (ushort_t*)alloc((size_t)4096*8192*2);
  ushort_t*  actb  = qkvb;        // [4096,4096] overlays qkvb+q2b (both dead by GEGLU time)
  float*     part  = (float*)hb;  // split-K partials [4][4096][1024] f32 overlay hb (dead otherwise)
  float*     part1 = part + (size_t)4096*1024;
  float*     part2 = part + (size_t)2*4096*1024;
  float*     part3 = part + (size_t)3*4096*1024;

  const float SC = 0.18033688011f;   // 0.125 * log2(e), folded into q-weight dequant
  QT qt;
  qt.w[0]=q1w;  qt.o[0]=wqkv1;               qt.n[0]=1024*1024; qt.os[0]=SC;  qt.pm[0]=0;
  qt.w[1]=k1w;  qt.o[1]=wqkv1+1024*1024;     qt.n[1]=1024*1024; qt.os[1]=1.f; qt.pm[1]=0;
  qt.w[2]=v1w;  qt.o[2]=wqkv1+2*1024*1024;   qt.n[2]=1024*1024; qt.os[2]=1.f; qt.pm[2]=0;
  qt.w[3]=o1w;  qt.o[3]=o1d;                 qt.n[3]=1024*1024; qt.os[3]=1.f; qt.pm[3]=0;
  qt.w[4]=q2w;  qt.o[4]=q2d;                 qt.n[4]=1024*1024; qt.os[4]=SC;  qt.pm[4]=0;
  qt.w[5]=k2w;  qt.o[5]=wkv2;                qt.n[5]=1024*768;  qt.os[5]=1.f; qt.pm[5]=0;
  qt.w[6]=v2w;  qt.o[6]=wkv2+1024*768;       qt.n[6]=1024*768;  qt.os[6]=1.f; qt.pm[6]=0;
  qt.w[7]=o2w;  qt.o[7]=o2d;                 qt.n[7]=1024*1024; qt.os[7]=1.f; qt.pm[7]=0;
  qt.w[8]=ff1w; qt.o[8]=f1d;                 qt.n[8]=8192*1024; qt.os[8]=1.f; qt.pm[8]=1;
  qt.w[9]=ff2w; qt.o[9]=f2d;                 qt.n[9]=1024*4096; qt.os[9]=1.f; qt.pm[9]=0;

  init_k<<<1, 64, 0, stream>>>(slots);
  minmax_k<<<dim3(256,10), 256, 0, stream>>>(qt, slots);
  dequant_k<<<dim3(256,10), 256, 0, stream>>>(qt, slots);
  f2b_k<<<64, 256, 0, stream>>>(ctx, ctxb, 154*768/4);

  // --- block 1: self attention ---
  ln_k<<<4096, 256, 0, stream>>>(x, ln1g, ln1b, lnb);
  gemm_k<<<dim3(24, 16), 512, 0, stream>>>(lnb, wqkv1, nullptr, nullptr,
                                           nullptr, qkvb, 4096, 3072, 1024, 1024, 1024);
  vtrans_k<<<dim3(16, 32), 256, 0, stream>>>(qkvb, vt1, 2048, 3072, 2048, 2048);
  attn_k<<<dim3(16, 32), 512, 0, stream>>>(qkvb, qkvb+1024, vt1, atb,
                                           2048, 2048, 3072, 3072, 2048);
  // o1 split-K=4 (partials overlay hb) -> fused reduce4 + LN2
  gemm_k<<<dim3(8, 16, 4), 512, 0, stream>>>(atb, o1d, nullptr, nullptr,
                                             part, nullptr, 4096, 1024, 256, 1024, 1024);
  reduce4_ln_k<<<4096, 256, 0, stream>>>(part, part1, part2, part3, o1b, x,
                                         ln2g, ln2b, x1, lnb);

  // --- block 2: cross attention ---
  gemm_k<<<dim3(8, 16, 4), 512, 0, stream>>>(lnb, q2d, nullptr, nullptr,
                                             part, nullptr, 4096, 1024, 256, 1024, 1024);
  reduce4_k<<<2048, 256, 0, stream>>>(part, part1, part2, part3, nullptr, nullptr,
                                      nullptr, q2b, 4096*1024/4);
  gemm_k<<<dim3(16, 1), 512, 0, stream>>>(ctxb, wkv2, nullptr, nullptr,
                                          nullptr, kvb, 154, 2048, 768, 768, 768);
  vtrans_k<<<dim3(1, 32), 256, 0, stream>>>(kvb, vt2, 77, 2048, 1024, 96);
  attn_k<<<dim3(16, 32), 512, 0, stream>>>(q2b, kvb, vt2, atb,
                                           2048, 77, 1024, 2048, 96);
  // o2 split-K=4 -> fused reduce4 + LN3
  gemm_k<<<dim3(8, 16, 4), 512, 0, stream>>>(atb, o2d, nullptr, nullptr,
                                             part, nullptr, 4096, 1024, 256, 1024, 1024);
  reduce4_ln_k<<<4096, 256, 0, stream>>>(part, part1, part2, part3, o2b, x1,
                                         ln3g, ln3b, x2, lnb);

  // --- block 3: GEGLU FF (ff1 + geglu fused, register-only epilogue) ---
  gemm_ff1_k<<<dim3(64, 16), 512, 0, stream>>>(lnb, f1d, ff1b, actb);
  // ff2 split-K=4 (partials overlay hb): 512 blocks = 2 blocks/CU
  gemm_k<<<dim3(8, 16, 4), 512, 0, stream>>>(actb, f2d, nullptr, nullptr,
                                             part, nullptr, 4096, 1024, 1024, 4096, 4096);
  reduce4_k<<<2048, 256, 0, stream>>>(part, part1, part2, part3, ff2b, x2,
                                      (float*)d_out, nullptr, 4096*1024/4);
}

// Round 22
// 520.875 us; speedup vs baseline: 1.0413x; 1.0413x over previous
//
#include <hip/hip_runtime.h>
#include <cstdint>
#include <cstddef>

typedef unsigned short ushort_t;
typedef short s16x8 __attribute__((ext_vector_type(8)));
typedef float f32x4 __attribute__((ext_vector_type(4)));
typedef unsigned u32x4 __attribute__((ext_vector_type(4)));

#define MFMA(A,B,C) __builtin_amdgcn_mfma_f32_16x16x32_bf16((A),(B),(C),0,0,0)

__device__ __forceinline__ float b2f(ushort_t h){ return __uint_as_float(((unsigned)h)<<16); }
__device__ __forceinline__ ushort_t f2b(float f){
  unsigned u = __float_as_uint(f);
  u += 0x7FFFu + ((u >> 16) & 1u);
  return (ushort_t)(u >> 16);
}
// monotone float<->uint encoding for atomic min/max
__device__ __forceinline__ unsigned f2o(float f){
  unsigned u = __float_as_uint(f);
  return (u & 0x80000000u) ? ~u : (u | 0x80000000u);
}
__device__ __forceinline__ float o2f(unsigned u){
  unsigned b = (u & 0x80000000u) ? (u & 0x7FFFFFFFu) : ~u;
  return __uint_as_float(b);
}

struct QT { const float* w[10]; ushort_t* o[10]; int n[10]; float os[10]; int pm[10]; };

__global__ void init_k(unsigned* slots){
  int t = threadIdx.x;
  if (t < 20) slots[t] = (t & 1) ? 0u : 0xFFFFFFFFu;
}

__global__ __launch_bounds__(256) void minmax_k(QT qt, unsigned* slots){
  int t = blockIdx.y;
  const float4* w = (const float4*)qt.w[t];
  int n4 = qt.n[t] >> 2;
  float mn = 3.4e38f, mx = -3.4e38f;
  for (int i = blockIdx.x*256 + threadIdx.x; i < n4; i += gridDim.x*256){
    float4 v = w[i];
    mn = fminf(mn, fminf(fminf(v.x, v.y), fminf(v.z, v.w)));
    mx = fmaxf(mx, fmaxf(fmaxf(v.x, v.y), fmaxf(v.z, v.w)));
  }
  #pragma unroll
  for (int o = 1; o < 64; o <<= 1){
    mn = fminf(mn, __shfl_xor(mn, o));
    mx = fmaxf(mx, __shfl_xor(mx, o));
  }
  __shared__ float smn[4], smx[4];
  int wv = threadIdx.x >> 6;
  if ((threadIdx.x & 63) == 0){ smn[wv] = mn; smx[wv] = mx; }
  __syncthreads();
  if (threadIdx.x == 0){
    mn = fminf(fminf(smn[0], smn[1]), fminf(smn[2], smn[3]));
    mx = fmaxf(fmaxf(smx[0], smx[1]), fmaxf(smx[2], smx[3]));
    atomicMin(&slots[2*t], f2o(mn));
    atomicMax(&slots[2*t+1], f2o(mx));
  }
}

// dequant with optional hidden/gate 32-row interleave (pm=1).
__global__ __launch_bounds__(256) void dequant_k(QT qt, const unsigned* __restrict__ slots){
  int t = blockIdx.y;
  float mn = o2f(slots[2*t]), mx = o2f(slots[2*t+1]);
  float delta = (mx - mn) * (1.f/255.f);
  float zp = rintf(-mn / delta);
  float osc = qt.os[t];
  int pm = qt.pm[t];
  const float4* w = (const float4*)qt.w[t];
  ushort4* o = (ushort4*)qt.o[t];
  int n4 = qt.n[t] >> 2;
  for (int i = blockIdx.x*256 + threadIdx.x; i < n4; i += gridDim.x*256){
    float4 v = w[i];
    ushort4 r;
    float q;
    q = fminf(fmaxf(rintf(v.x/delta) + zp, 0.f), 255.f); r.x = f2b((q - zp)*delta*osc);
    q = fminf(fmaxf(rintf(v.y/delta) + zp, 0.f), 255.f); r.y = f2b((q - zp)*delta*osc);
    q = fminf(fmaxf(rintf(v.z/delta) + zp, 0.f), 255.f); r.z = f2b((q - zp)*delta*osc);
    q = fminf(fmaxf(rintf(v.w/delta) + zp, 0.f), 255.f); r.w = f2b((q - zp)*delta*osc);
    size_t oi = i;
    if (pm){
      int row = i >> 8, c4 = i & 255;
      int nr = (row < 4096) ? ((row >> 5) << 6) + (row & 31)
                            : (((row - 4096) >> 5) << 6) + 32 + ((row - 4096) & 31);
      oi = (size_t)nr*256 + c4;
    }
    o[oi] = r;
  }
}

__global__ __launch_bounds__(256) void f2b_k(const float* __restrict__ in, ushort_t* __restrict__ out, int n4){
  for (int i = blockIdx.x*256 + threadIdx.x; i < n4; i += gridDim.x*256){
    float4 v = ((const float4*)in)[i];
    ushort4 r; r.x = f2b(v.x); r.y = f2b(v.y); r.z = f2b(v.z); r.w = f2b(v.w);
    ((ushort4*)out)[i] = r;
  }
}

// LayerNorm over rows of 1024 f32 -> bf16. One block per row.
__global__ __launch_bounds__(256) void ln_k(const float* __restrict__ x, const float* __restrict__ g,
                                            const float* __restrict__ b, ushort_t* __restrict__ out){
  int row = blockIdx.x, tid = threadIdx.x;
  float4 v = ((const float4*)(x + (size_t)row*1024))[tid];
  float s  = v.x + v.y + v.z + v.w;
  float s2 = v.x*v.x + v.y*v.y + v.z*v.z + v.w*v.w;
  #pragma unroll
  for (int o = 1; o < 64; o <<= 1){ s += __shfl_xor(s, o); s2 += __shfl_xor(s2, o); }
  __shared__ float rs[4], rs2[4];
  int wv = tid >> 6;
  if ((tid & 63) == 0){ rs[wv] = s; rs2[wv] = s2; }
  __syncthreads();
  s = rs[0]+rs[1]+rs[2]+rs[3]; s2 = rs2[0]+rs2[1]+rs2[2]+rs2[3];
  float mu = s * (1.f/1024.f);
  float var = s2 * (1.f/1024.f) - mu*mu;
  float rstd = rsqrtf(var + 1e-5f);
  float4 gv = ((const float4*)g)[tid], bv = ((const float4*)b)[tid];
  ushort4 r;
  r.x = f2b((v.x - mu)*rstd*gv.x + bv.x);
  r.y = f2b((v.y - mu)*rstd*gv.y + bv.y);
  r.z = f2b((v.z - mu)*rstd*gv.z + bv.z);
  r.w = f2b((v.w - mu)*rstd*gv.w + bv.w);
  ((ushort4*)(out + (size_t)row*1024))[tid] = r;
}

// Fused: x = p0+p1+bias+resid (write f32), then LayerNorm(x)*g+b -> bf16. One block per row.
__global__ __launch_bounds__(256) void reduce_ln_k(
    const float* __restrict__ p0, const float* __restrict__ p1,
    const float* __restrict__ bias, const float* __restrict__ resid,
    const float* __restrict__ lng, const float* __restrict__ lnb_,
    float* __restrict__ xout, ushort_t* __restrict__ lnout)
{
  int row = blockIdx.x, tid = threadIdx.x;
  size_t bi = (size_t)row*256 + tid;
  float4 a = ((const float4*)p0)[bi];
  float4 b = ((const float4*)p1)[bi];
  float4 r = ((const float4*)resid)[bi];
  float4 bb = ((const float4*)bias)[tid];
  float4 v;
  v.x = a.x + b.x + r.x + bb.x;
  v.y = a.y + b.y + r.y + bb.y;
  v.z = a.z + b.z + r.z + bb.z;
  v.w = a.w + b.w + r.w + bb.w;
  ((float4*)xout)[bi] = v;
  float s  = v.x + v.y + v.z + v.w;
  float s2 = v.x*v.x + v.y*v.y + v.z*v.z + v.w*v.w;
  #pragma unroll
  for (int o = 1; o < 64; o <<= 1){ s += __shfl_xor(s, o); s2 += __shfl_xor(s2, o); }
  __shared__ float rs[4], rs2[4];
  int wv = tid >> 6;
  if ((tid & 63) == 0){ rs[wv] = s; rs2[wv] = s2; }
  __syncthreads();
  s = rs[0]+rs[1]+rs[2]+rs[3]; s2 = rs2[0]+rs2[1]+rs2[2]+rs2[3];
  float mu = s * (1.f/1024.f);
  float var = s2 * (1.f/1024.f) - mu*mu;
  float rstd = rsqrtf(var + 1e-5f);
  float4 gv = ((const float4*)lng)[tid], bv = ((const float4*)lnb_)[tid];
  ushort4 o;
  o.x = f2b((v.x - mu)*rstd*gv.x + bv.x);
  o.y = f2b((v.y - mu)*rstd*gv.y + bv.y);
  o.z = f2b((v.z - mu)*rstd*gv.z + bv.z);
  o.w = f2b((v.w - mu)*rstd*gv.w + bv.w);
  ((ushort4*)(lnout + (size_t)row*1024))[tid] = o;
}

// C[M,N] = A[M,K_total] @ W[N,K_total]^T (+bias)(+resid). 256x128 tile, BK=32,
// 8 waves (4Mx2N). 3-deep ring + counted vmcnt across raw s_barrier (T4).
__global__ __launch_bounds__(512) void gemm_k(
    const ushort_t* __restrict__ A, const ushort_t* __restrict__ W,
    const float* __restrict__ bias, const float* __restrict__ resid,
    float* __restrict__ outF, ushort_t* __restrict__ outB,
    int M, int N, int K, int lda, int ldw)
{
  __shared__ ushort_t As[3][256*32];
  __shared__ ushort_t Bs[3][128*32];
  const int tid = threadIdx.x;
  const int lane = tid & 63, wv = tid >> 6;
  const int g = lane >> 4, qi = lane & 15;

  const int gx = gridDim.x, gy = gridDim.y;
  const int lid = blockIdx.x + blockIdx.y * gx;
  int m0, n0;
  if (((gx & 3) | (gy & 1)) == 0){
    const int w = gx >> 2, h = gy >> 1;
    const int xcd = lid & 7, o = lid >> 3;
    const int cx = xcd & 3, cy = xcd >> 2;
    n0 = (cx * w + (o % w)) * 128;
    m0 = (cy * h + (o / w)) * 256;
  } else {
    n0 = blockIdx.x * 128;
    m0 = blockIdx.y * 256;
  }

  const int koff = blockIdx.z * K;
  if (gridDim.z > 1) outF += (size_t)blockIdx.z * M * N;

  const int wr = (wv >> 1) * 64, wc = (wv & 1) * 64;
  f32x4 acc[4][4] = {};

  const int ra0 = tid >> 2,        sa0 = (tid & 3) ^ ((ra0 >> 1) & 3);
  const int ra1 = (512+tid) >> 2,  sa1 = ((512+tid) & 3) ^ ((ra1 >> 1) & 3);
  const int aA0 = (m0 + ra0 < M) ? m0 + ra0 : M - 1;
  const int aA1 = (m0 + ra1 < M) ? m0 + ra1 : M - 1;
  const size_t dA0 = (size_t)tid*8, dA1 = (size_t)(512+tid)*8, dB0 = (size_t)tid*8;

  #define GSTAGE(bi_, kt_) do {                                                    \
    __builtin_amdgcn_global_load_lds(                                              \
      (const __attribute__((address_space(1))) void*)(A + (size_t)aA0*lda + koff + (kt_) + sa0*8), \
      (__attribute__((address_space(3))) void*)(&As[bi_][dA0]), 16, 0, 0);         \
    __builtin_amdgcn_global_load_lds(                                              \
      (const __attribute__((address_space(1))) void*)(A + (size_t)aA1*lda + koff + (kt_) + sa1*8), \
      (__attribute__((address_space(3))) void*)(&As[bi_][dA1]), 16, 0, 0);         \
    __builtin_amdgcn_global_load_lds(                                              \
      (const __attribute__((address_space(1))) void*)(W + (size_t)(n0 + ra0)*ldw + koff + (kt_) + sa0*8), \
      (__attribute__((address_space(3))) void*)(&Bs[bi_][dB0]), 16, 0, 0);         \
  } while(0)

  const int nt = K >> 5;
  GSTAGE(0, 0);
  if (nt > 1) GSTAGE(1, 32);
  if (nt > 1) asm volatile("s_waitcnt vmcnt(3)" ::: "memory");
  else        asm volatile("s_waitcnt vmcnt(0)" ::: "memory");
  __builtin_amdgcn_s_barrier();
  __builtin_amdgcn_sched_barrier(0);

  int bi = 0;
  for (int t = 0; t < nt; ++t){
    int b2 = bi + 2; if (b2 >= 3) b2 -= 3;
    if (t + 2 < nt) GSTAGE(b2, (t + 2) << 5);
    s16x8 af[4], bfr[4];
    #pragma unroll
    for (int mi = 0; mi < 4; ++mi){
      int row = wr + mi*16 + qi;
      int sl = g ^ ((row >> 1) & 3);
      af[mi] = *(const s16x8*)(&As[bi][row*32 + sl*8]);
    }
    #pragma unroll
    for (int ni = 0; ni < 4; ++ni){
      int row = wc + ni*16 + qi;
      int sl = g ^ ((row >> 1) & 3);
      bfr[ni] = *(const s16x8*)(&Bs[bi][row*32 + sl*8]);
    }
    __builtin_amdgcn_s_setprio(1);
    #pragma unroll
    for (int mi = 0; mi < 4; ++mi)
      #pragma unroll
      for (int ni = 0; ni < 4; ++ni)
        acc[mi][ni] = MFMA(af[mi], bfr[ni], acc[mi][ni]);
    __builtin_amdgcn_s_setprio(0);
    if (t + 1 < nt){
      if (t + 2 < nt) asm volatile("s_waitcnt vmcnt(3)" ::: "memory");
      else            asm volatile("s_waitcnt vmcnt(0)" ::: "memory");
      __builtin_amdgcn_s_barrier();
      __builtin_amdgcn_sched_barrier(0);
    }
    bi += 1; if (bi >= 3) bi -= 3;
  }
  #undef GSTAGE

  #pragma unroll
  for (int mi = 0; mi < 4; ++mi){
    #pragma unroll
    for (int r = 0; r < 4; ++r){
      int row = m0 + wr + mi*16 + g*4 + r;
      if (row >= M) continue;
      #pragma unroll
      for (int ni = 0; ni < 4; ++ni){
        int col = n0 + wc + ni*16 + qi;
        float v = acc[mi][ni][r];
        if (bias)  v += bias[col];
        if (resid) v += resid[(size_t)row*N + col];
        if (outF)  outF[(size_t)row*N + col] = v;
        else       outB[(size_t)row*N + col] = f2b(v);
      }
    }
  }
}

// ff1 + fused GEGLU, register-only epilogue (32-row interleaved Wp; dequant pm=1).
__global__ __launch_bounds__(512) void gemm_ff1_k(
    const ushort_t* __restrict__ A, const ushort_t* __restrict__ W,
    const float* __restrict__ biasHG, ushort_t* __restrict__ out)
{
  __shared__ ushort_t As[3][256*32];
  __shared__ ushort_t Bs[3][128*32];
  const int tid = threadIdx.x;
  const int lane = tid & 63, wv = tid >> 6;
  const int g = lane >> 4, qi = lane & 15;
  const int lda = 1024, ldw = 1024;

  const int gx = gridDim.x;   // 64
  const int gy = gridDim.y;   // 16
  const int lid = blockIdx.x + blockIdx.y * gx;
  const int w = gx >> 2, h = gy >> 1;
  const int xcd = lid & 7, o = lid >> 3;
  const int cx = xcd & 3, cy = xcd >> 2;
  const int n0 = (cx * w + (o % w)) * 128;
  const int m0 = (cy * h + (o / w)) * 256;

  const int wr = (wv >> 1) * 64, wc = (wv & 1) * 64;
  f32x4 acc[4][4] = {};

  const int ra0 = tid >> 2,        sa0 = (tid & 3) ^ ((ra0 >> 1) & 3);
  const int ra1 = (512+tid) >> 2,  sa1 = ((512+tid) & 3) ^ ((ra1 >> 1) & 3);
  const int aA0 = m0 + ra0, aA1 = m0 + ra1;
  const size_t dA0 = (size_t)tid*8, dA1 = (size_t)(512+tid)*8, dB0 = (size_t)tid*8;

  #define GSTAGEF(bi_, kt_) do {                                                   \
    __builtin_amdgcn_global_load_lds(                                              \
      (const __attribute__((address_space(1))) void*)(A + (size_t)aA0*lda + (kt_) + sa0*8), \
      (__attribute__((address_space(3))) void*)(&As[bi_][dA0]), 16, 0, 0);         \
    __builtin_amdgcn_global_load_lds(                                              \
      (const __attribute__((address_space(1))) void*)(A + (size_t)aA1*lda + (kt_) + sa1*8), \
      (__attribute__((address_space(3))) void*)(&As[bi_][dA1]), 16, 0, 0);         \
    __builtin_amdgcn_global_load_lds(                                              \
      (const __attribute__((address_space(1))) void*)(W + (size_t)(n0 + ra0)*ldw + (kt_) + sa0*8), \
      (__attribute__((address_space(3))) void*)(&Bs[bi_][dB0]), 16, 0, 0);         \
  } while(0)

  const int nt = 1024 >> 5;
  GSTAGEF(0, 0);
  GSTAGEF(1, 32);
  asm volatile("s_waitcnt vmcnt(3)" ::: "memory");
  __builtin_amdgcn_s_barrier();
  __builtin_amdgcn_sched_barrier(0);

  int bi = 0;
  for (int t = 0; t < nt; ++t){
    int b2 = bi + 2; if (b2 >= 3) b2 -= 3;
    if (t + 2 < nt) GSTAGEF(b2, (t + 2) << 5);
    s16x8 af[4], bfr[4];
    #pragma unroll
    for (int mi = 0; mi < 4; ++mi){
      int row = wr + mi*16 + qi;
      int sl = g ^ ((row >> 1) & 3);
      af[mi] = *(const s16x8*)(&As[bi][row*32 + sl*8]);
    }
    #pragma unroll
    for (int ni = 0; ni < 4; ++ni){
      int row = wc + ni*16 + qi;
      int sl = g ^ ((row >> 1) & 3);
      bfr[ni] = *(const s16x8*)(&Bs[bi][row*32 + sl*8]);
    }
    __builtin_amdgcn_s_setprio(1);
    #pragma unroll
    for (int mi = 0; mi < 4; ++mi)
      #pragma unroll
      for (int ni = 0; ni < 4; ++ni)
        acc[mi][ni] = MFMA(af[mi], bfr[ni], acc[mi][ni]);
    __builtin_amdgcn_s_setprio(0);
    if (t + 1 < nt){
      if (t + 2 < nt) asm volatile("s_waitcnt vmcnt(3)" ::: "memory");
      else            asm volatile("s_waitcnt vmcnt(0)" ::: "memory");
      __builtin_amdgcn_s_barrier();
      __builtin_amdgcn_sched_barrier(0);
    }
    bi += 1; if (bi >= 3) bi -= 3;
  }
  #undef GSTAGEF

  const int jw = (n0 + wc) >> 1;
  #pragma unroll
  for (int mi = 0; mi < 4; ++mi){
    #pragma unroll
    for (int r = 0; r < 4; ++r){
      int row = m0 + wr + mi*16 + g*4 + r;
      #pragma unroll
      for (int ni = 0; ni < 2; ++ni){
        int j = jw + ni*16 + qi;
        float hv = acc[mi][ni][r]   + biasHG[j];
        float gg = acc[mi][ni+2][r] + biasHG[4096 + j];
        float tt = 0.7978845608f*(gg + 0.044715f*gg*gg*gg);
        float e  = __builtin_amdgcn_exp2f(2.885390082f*tt);   // e^(2t)
        float th = 1.f - 2.f/(e + 1.f);
        float ge = 0.5f*gg*(1.f + th);
        out[(size_t)row*4096 + j] = f2b(hv * ge);
      }
    }
  }
}

// out = p0 + p1 (+bias) (+resid); outF f32 or outB bf16. Row width 1024 f32.
__global__ __launch_bounds__(256) void reduce_k(const float* __restrict__ p0, const float* __restrict__ p1,
                                                const float* __restrict__ bias, const float* __restrict__ resid,
                                                float* __restrict__ outF, ushort_t* __restrict__ outB, int n4){
  for (int i = blockIdx.x*256 + threadIdx.x; i < n4; i += gridDim.x*256){
    float4 a = ((const float4*)p0)[i];
    float4 b = ((const float4*)p1)[i];
    float4 v;
    v.x = a.x + b.x; v.y = a.y + b.y; v.z = a.z + b.z; v.w = a.w + b.w;
    if (bias){
      float4 bb = ((const float4*)bias)[i & 255];
      v.x += bb.x; v.y += bb.y; v.z += bb.z; v.w += bb.w;
    }
    if (resid){
      float4 r = ((const float4*)resid)[i];
      v.x += r.x; v.y += r.y; v.z += r.z; v.w += r.w;
    }
    if (outF) ((float4*)outF)[i] = v;
    else {
      ushort4 o; o.x = f2b(v.x); o.y = f2b(v.y); o.z = f2b(v.z); o.w = f2b(v.w);
      ((ushort4*)outB)[i] = o;
    }
  }
}

// out = p0+p1+p2+p3 (+bias) (+resid); outF f32 or outB bf16. Row width 1024 f32.
__global__ __launch_bounds__(256) void reduce4_k(const float* __restrict__ p0, const float* __restrict__ p1,
                                                 const float* __restrict__ p2, const float* __restrict__ p3,
                                                 const float* __restrict__ bias, const float* __restrict__ resid,
                                                 float* __restrict__ outF, ushort_t* __restrict__ outB, int n4){
  for (int i = blockIdx.x*256 + threadIdx.x; i < n4; i += gridDim.x*256){
    float4 a = ((const float4*)p0)[i];
    float4 b = ((const float4*)p1)[i];
    float4 c = ((const float4*)p2)[i];
    float4 d = ((const float4*)p3)[i];
    float4 v;
    v.x = (a.x + b.x) + (c.x + d.x);
    v.y = (a.y + b.y) + (c.y + d.y);
    v.z = (a.z + b.z) + (c.z + d.z);
    v.w = (a.w + b.w) + (c.w + d.w);
    if (bias){
      float4 bb = ((const float4*)bias)[i & 255];
      v.x += bb.x; v.y += bb.y; v.z += bb.z; v.w += bb.w;
    }
    if (resid){
      float4 r = ((const float4*)resid)[i];
      v.x += r.x; v.y += r.y; v.z += r.z; v.w += r.w;
    }
    if (outF) ((float4*)outF)[i] = v;
    else {
      ushort4 o; o.x = f2b(v.x); o.y = f2b(v.y); o.z = f2b(v.z); o.w = f2b(v.w);
      ((ushort4*)outB)[i] = o;
    }
  }
}

// Transpose V into Vt[b][h][64][nk_pad] (zero-padded). One block per (n-tile of 128, b*16+h).
__global__ __launch_bounds__(256) void vtrans_k(const ushort_t* __restrict__ src, ushort_t* __restrict__ dst,
                                                int rows, int stride, int col_off, int nk_pad){
  __shared__ ushort_t ldst[64*130];
  int n0 = blockIdx.x * 128;
  int b = blockIdx.y >> 4, h = blockIdx.y & 15;
  const ushort_t* s = src + (size_t)b*rows*stride + col_off + h*64;
  for (int idx = threadIdx.x; idx < 128*64; idx += 256){
    int n = idx >> 6, d = idx & 63;
    int ng = n0 + n;
    ushort_t v = (ng < rows) ? s[(size_t)ng*stride + d] : (ushort_t)0;
    ldst[d*130 + n] = v;
  }
  __syncthreads();
  ushort_t* o = dst + (size_t)(b*16 + h)*64*nk_pad;
  for (int idx = threadIdx.x; idx < 64*128; idx += 256){
    int d = idx >> 7, n = idx & 127;
    if (n0 + n < nk_pad) o[(size_t)d*nk_pad + n0 + n] = ldst[d*130 + n];
  }
}

// Flash attention, H=16, DH=64. Block = 8 waves; wave owns 16 q rows (128 q/block).
// KVBLK=32 staged in LDS (dbuf): waves 0-3 stage K, waves 4-7 stage V.
// Swapped QK^T (scale pre-folded, log2 domain); native v_exp; exact rescale-skip;
// deferred per-lane l; v_cvt_pk pack; setprio around MFMA clusters.
__global__ __launch_bounds__(512) void attn_k(
    const ushort_t* __restrict__ Q, const ushort_t* __restrict__ Kp, const ushort_t* __restrict__ Vt,
    ushort_t* __restrict__ O, int nq, int nk, int qstride, int kvstride, int nk_pad)
{
  __shared__ ushort_t Ks[2][32*64];   // [key 32][d 64], 8 slots/row, XOR row&7
  __shared__ ushort_t Vs[2][64*32];   // [d 64][key 32], 4 slots/row, XOR (row>>1)&3
  const int tid = threadIdx.x, lane = tid & 63, wv = tid >> 6;
  const int g = lane >> 4, qi = lane & 15;
  const int b = blockIdx.y >> 4, h = blockIdx.y & 15;
  const int q0 = blockIdx.x*128 + wv*16;

  const ushort_t* Qr = Q + (size_t)(b*nq + q0 + qi)*qstride + h*64;
  s16x8 qf0 = *(const s16x8*)(Qr + g*8);
  s16x8 qf1 = *(const s16x8*)(Qr + 32 + g*8);
  const ushort_t* Kb = Kp + (size_t)b*nk*kvstride + h*64;
  const ushort_t* Vb = Vt + (size_t)(b*16 + h)*64*nk_pad;

  const int krow = (wv & 3)*8 + (lane >> 3);
  const int kgsl = (lane & 7) ^ (krow & 7);
  const int vrow = (wv & 3)*16 + (lane >> 2);
  const int vgsl = (lane & 3) ^ ((vrow >> 1) & 3);

  #define STAGE(buf, kb_) do {                                                   \
    if (wv < 4){                                                                 \
      int kr_ = (kb_) + krow; if (kr_ >= nk) kr_ = nk - 1;                       \
      __builtin_amdgcn_global_load_lds(                                          \
        (const __attribute__((address_space(1))) void*)(Kb + (size_t)kr_*kvstride + kgsl*8), \
        (__attribute__((address_space(3))) void*)(&Ks[buf][(size_t)(wv&3)*512]), 16, 0, 0); \
    } else {                                                                     \
      __builtin_amdgcn_global_load_lds(                                          \
        (const __attribute__((address_space(1))) void*)(Vb + (size_t)vrow*nk_pad + (kb_) + vgsl*8), \
        (__attribute__((address_space(3))) void*)(&Vs[buf][(size_t)(wv&3)*512]), 16, 0, 0); \
    }                                                                            \
  } while(0)

  const int nkp = (nk + 31) & ~31;
  f32x4 ot[4] = {};
  float m_run = -1e30f, lsum = 0.f;

  const int ks0 = (g     ^ (qi & 7)) * 8;
  const int ks1 = ((4+g) ^ (qi & 7)) * 8;
  const int vs0 = (g ^ ((qi >> 1) & 3)) * 8;

  STAGE(0, 0);
  asm volatile("s_waitcnt vmcnt(0)" ::: "memory");
  __syncthreads();
  int cur = 0;
  for (int kb = 0; kb < nkp; kb += 32){
    if (kb + 32 < nkp) STAGE(cur^1, kb + 32);
    s16x8 ka0 = *(const s16x8*)(&Ks[cur][(qi)*64      + ks0]);
    s16x8 ka1 = *(const s16x8*)(&Ks[cur][(qi)*64      + ks1]);
    s16x8 kb0 = *(const s16x8*)(&Ks[cur][(16+qi)*64   + ks0]);
    s16x8 kb1 = *(const s16x8*)(&Ks[cur][(16+qi)*64   + ks1]);
    s16x8 vf0 = *(const s16x8*)(&Vs[cur][(qi)*32      + vs0]);
    s16x8 vf1 = *(const s16x8*)(&Vs[cur][(16+qi)*32   + vs0]);
    s16x8 vf2 = *(const s16x8*)(&Vs[cur][(32+qi)*32   + vs0]);
    s16x8 vf3 = *(const s16x8*)(&Vs[cur][(48+qi)*32   + vs0]);

    f32x4 st0 = {}, st1 = {};
    __builtin_amdgcn_s_setprio(1);
    st0 = MFMA(ka0, qf0, st0);
    st0 = MFMA(ka1, qf1, st0);
    st1 = MFMA(kb0, qf0, st1);
    st1 = MFMA(kb1, qf1, st1);
    __builtin_amdgcn_s_setprio(0);
    float s[8];
    #pragma unroll
    for (int r = 0; r < 4; ++r){ s[r] = st0[r]; s[4+r] = st1[r]; }   // scale pre-folded
    if (kb + 32 > nk){
      #pragma unroll
      for (int r = 0; r < 4; ++r){
        if (kb + 4*g + r >= nk)      s[r]   = -1e30f;
        if (kb + 16 + 4*g + r >= nk) s[4+r] = -1e30f;
      }
    }
    float m1 = fmaxf(fmaxf(s[0], s[1]), s[2]);
    float m2 = fmaxf(fmaxf(s[3], s[4]), s[5]);
    float bm = fmaxf(fmaxf(m1, m2), fmaxf(s[6], s[7]));
    bm = fmaxf(bm, __shfl_xor(bm, 16));
    bm = fmaxf(bm, __shfl_xor(bm, 32));
    if (!__all(bm <= m_run)){
      float m_new = fmaxf(m_run, bm);
      float fac = __builtin_amdgcn_exp2f(m_run - m_new);
      lsum *= fac;
      #pragma unroll
      for (int dd = 0; dd < 4; ++dd)
        #pragma unroll
        for (int r = 0; r < 4; ++r) ot[dd][r] *= fac;
      m_run = m_new;
    }
    float p[8], ps = 0.f;
    #pragma unroll
    for (int i = 0; i < 8; ++i){ p[i] = __builtin_amdgcn_exp2f(s[i] - m_run); ps += p[i]; }
    lsum += ps;
    unsigned pk[4];
    #pragma unroll
    for (int r = 0; r < 4; ++r)
      asm("v_cvt_pk_bf16_f32 %0, %1, %2" : "=v"(pk[r]) : "v"(p[r]), "v"(p[4+r]));
    int srcbase = ((2*g) & 3) * 16 + qi;
    unsigned sh0[4], sh1[4];
    #pragma unroll
    for (int r = 0; r < 4; ++r){
      sh0[r] = (unsigned)__shfl((int)pk[r], srcbase);
      sh1[r] = (unsigned)__shfl((int)pk[r], srcbase + 16);
    }
    unsigned sel = (g >> 1) ? 0x07060302u : 0x05040100u;
    u32x4 pw;
    pw[0] = __builtin_amdgcn_perm(sh0[1], sh0[0], sel);
    pw[1] = __builtin_amdgcn_perm(sh0[3], sh0[2], sel);
    pw[2] = __builtin_amdgcn_perm(sh1[1], sh1[0], sel);
    pw[3] = __builtin_amdgcn_perm(sh1[3], sh1[2], sel);
    s16x8 pf = __builtin_bit_cast(s16x8, pw);
    __builtin_amdgcn_s_setprio(1);
    ot[0] = MFMA(vf0, pf, ot[0]);
    ot[1] = MFMA(vf1, pf, ot[1]);
    ot[2] = MFMA(vf2, pf, ot[2]);
    ot[3] = MFMA(vf3, pf, ot[3]);
    __builtin_amdgcn_s_setprio(0);

    asm volatile("s_waitcnt vmcnt(0)" ::: "memory");
    __syncthreads();
    cur ^= 1;
  }
  #undef STAGE
  float l = lsum;
  l += __shfl_xor(l, 16);
  l += __shfl_xor(l, 32);
  float inv = 1.f / l;
  ushort_t* Or = O + (size_t)(b*nq + q0 + qi)*1024 + h*64;
  #pragma unroll
  for (int dd = 0; dd < 4; ++dd)
    #pragma unroll
    for (int r = 0; r < 4; ++r)
      Or[dd*16 + 4*g + r] = f2b(ot[dd][r] * inv);
}

extern "C" void kernel_launch(void* const* d_in, const int* in_sizes, int n_in,
                              void* d_out, int out_size, void* d_ws, size_t ws_size,
                              hipStream_t stream)
{
  const float* x    = (const float*)d_in[0];
  const float* ctx  = (const float*)d_in[1];
  const float* ln1g = (const float*)d_in[2];
  const float* ln1b = (const float*)d_in[3];
  const float* ln2g = (const float*)d_in[4];
  const float* ln2b = (const float*)d_in[5];
  const float* ln3g = (const float*)d_in[6];
  const float* ln3b = (const float*)d_in[7];
  const float* q1w  = (const float*)d_in[8];
  const float* k1w  = (const float*)d_in[9];
  const float* v1w  = (const float*)d_in[10];
  const float* o1w  = (const float*)d_in[11];
  const float* o1b  = (const float*)d_in[12];
  const float* q2w  = (const float*)d_in[13];
  const float* k2w  = (const float*)d_in[14];
  const float* v2w  = (const float*)d_in[15];
  const float* o2w  = (const float*)d_in[16];
  const float* o2b  = (const float*)d_in[17];
  const float* ff1w = (const float*)d_in[18];
  const float* ff1b = (const float*)d_in[19];
  const float* ff2w = (const float*)d_in[20];
  const float* ff2b = (const float*)d_in[21];

  char* base = (char*)d_ws;
  size_t off = 0;
  auto alloc = [&](size_t bytes) -> char* {
    char* p = base + off;
    off += (bytes + 255) & ~(size_t)255;
    return p;
  };
  unsigned*  slots = (unsigned*)alloc(80);
  ushort_t*  ctxb  = (ushort_t*)alloc((size_t)154*768*2);
  ushort_t*  wqkv1 = (ushort_t*)alloc((size_t)3072*1024*2);
  ushort_t*  o1d   = (ushort_t*)alloc((size_t)1024*1024*2);
  ushort_t*  q2d   = (ushort_t*)alloc((size_t)1024*1024*2);
  ushort_t*  wkv2  = (ushort_t*)alloc((size_t)2048*768*2);
  ushort_t*  o2d   = (ushort_t*)alloc((size_t)1024*1024*2);
  ushort_t*  f1d   = (ushort_t*)alloc((size_t)8192*1024*2);
  ushort_t*  f2d   = (ushort_t*)alloc((size_t)1024*4096*2);
  ushort_t*  lnb   = (ushort_t*)alloc((size_t)4096*1024*2);
  ushort_t*  qkvb  = (ushort_t*)alloc((size_t)4096*3072*2);
  ushort_t*  q2b   = (ushort_t*)alloc((size_t)4096*1024*2);
  ushort_t*  atb   = (ushort_t*)alloc((size_t)4096*1024*2);
  ushort_t*  kvb   = (ushort_t*)alloc((size_t)154*2048*2);
  ushort_t*  vt1   = (ushort_t*)alloc((size_t)2*16*64*2048*2);
  ushort_t*  vt2   = (ushort_t*)alloc((size_t)2*16*64*96*2);
  float*     x1    = (float*)alloc((size_t)4096*1024*4);
  float*     x2    = (float*)alloc((size_t)4096*1024*4);
  ushort_t*  hb    = (ushort_t*)alloc((size_t)4096*8192*2);
  ushort_t*  actb  = qkvb;        // [4096,4096] overlays qkvb+q2b (both dead by GEGLU time)
  float*     part  = (float*)hb;  // split-K partials overlay hb (dead otherwise)
  float*     part1 = part + (size_t)4096*1024;
  float*     part2 = part + (size_t)2*4096*1024;
  float*     part3 = part + (size_t)3*4096*1024;

  const float SC = 0.18033688011f;   // 0.125 * log2(e), folded into q-weight dequant
  QT qt;
  qt.w[0]=q1w;  qt.o[0]=wqkv1;               qt.n[0]=1024*1024; qt.os[0]=SC;  qt.pm[0]=0;
  qt.w[1]=k1w;  qt.o[1]=wqkv1+1024*1024;     qt.n[1]=1024*1024; qt.os[1]=1.f; qt.pm[1]=0;
  qt.w[2]=v1w;  qt.o[2]=wqkv1+2*1024*1024;   qt.n[2]=1024*1024; qt.os[2]=1.f; qt.pm[2]=0;
  qt.w[3]=o1w;  qt.o[3]=o1d;                 qt.n[3]=1024*1024; qt.os[3]=1.f; qt.pm[3]=0;
  qt.w[4]=q2w;  qt.o[4]=q2d;                 qt.n[4]=1024*1024; qt.os[4]=SC;  qt.pm[4]=0;
  qt.w[5]=k2w;  qt.o[5]=wkv2;                qt.n[5]=1024*768;  qt.os[5]=1.f; qt.pm[5]=0;
  qt.w[6]=v2w;  qt.o[6]=wkv2+1024*768;       qt.n[6]=1024*768;  qt.os[6]=1.f; qt.pm[6]=0;
  qt.w[7]=o2w;  qt.o[7]=o2d;                 qt.n[7]=1024*1024; qt.os[7]=1.f; qt.pm[7]=0;
  qt.w[8]=ff1w; qt.o[8]=f1d;                 qt.n[8]=8192*1024; qt.os[8]=1.f; qt.pm[8]=1;
  qt.w[9]=ff2w; qt.o[9]=f2d;                 qt.n[9]=1024*4096; qt.os[9]=1.f; qt.pm[9]=0;

  init_k<<<1, 64, 0, stream>>>(slots);
  minmax_k<<<dim3(256,10), 256, 0, stream>>>(qt, slots);
  dequant_k<<<dim3(256,10), 256, 0, stream>>>(qt, slots);
  f2b_k<<<64, 256, 0, stream>>>(ctx, ctxb, 154*768/4);

  // --- block 1: self attention ---
  ln_k<<<4096, 256, 0, stream>>>(x, ln1g, ln1b, lnb);
  gemm_k<<<dim3(24, 16), 512, 0, stream>>>(lnb, wqkv1, nullptr, nullptr,
                                           nullptr, qkvb, 4096, 3072, 1024, 1024, 1024);
  vtrans_k<<<dim3(16, 32), 256, 0, stream>>>(qkvb, vt1, 2048, 3072, 2048, 2048);
  attn_k<<<dim3(16, 32), 512, 0, stream>>>(qkvb, qkvb+1024, vt1, atb,
                                           2048, 2048, 3072, 3072, 2048);
  // o1 split-K=2 (partials overlay hb) -> fused reduce + LN2
  gemm_k<<<dim3(8, 16, 2), 512, 0, stream>>>(atb, o1d, nullptr, nullptr,
                                             part, nullptr, 4096, 1024, 512, 1024, 1024);
  reduce_ln_k<<<4096, 256, 0, stream>>>(part, part1, o1b, x, ln2g, ln2b, x1, lnb);

  // --- block 2: cross attention ---
  gemm_k<<<dim3(8, 16, 2), 512, 0, stream>>>(lnb, q2d, nullptr, nullptr,
                                             part, nullptr, 4096, 1024, 512, 1024, 1024);
  reduce_k<<<2048, 256, 0, stream>>>(part, part1, nullptr, nullptr, nullptr, q2b, 4096*1024/4);
  gemm_k<<<dim3(16, 1), 512, 0, stream>>>(ctxb, wkv2, nullptr, nullptr,
                                          nullptr, kvb, 154, 2048, 768, 768, 768);
  vtrans_k<<<dim3(1, 32), 256, 0, stream>>>(kvb, vt2, 77, 2048, 1024, 96);
  attn_k<<<dim3(16, 32), 512, 0, stream>>>(q2b, kvb, vt2, atb,
                                           2048, 77, 1024, 2048, 96);
  // o2 split-K=2 -> fused reduce + LN3
  gemm_k<<<dim3(8, 16, 2), 512, 0, stream>>>(atb, o2d, nullptr, nullptr,
                                             part, nullptr, 4096, 1024, 512, 1024, 1024);
  reduce_ln_k<<<4096, 256, 0, stream>>>(part, part1, o2b, x1, ln3g, ln3b, x2, lnb);

  // --- block 3: GEGLU FF (ff1 + geglu fused, register-only epilogue) ---
  gemm_ff1_k<<<dim3(64, 16), 512, 0, stream>>>(lnb, f1d, ff1b, actb);
  // ff2 split-K=4 (partials overlay hb): 512 blocks = 2 blocks/CU
  gemm_k<<<dim3(8, 16, 4), 512, 0, stream>>>(actb, f2d, nullptr, nullptr,
                                             part, nullptr, 4096, 1024, 1024, 4096, 4096);
  reduce4_k<<<2048, 256, 0, stream>>>(part, part1, part2, part3, ff2b, x2,
                                      (float*)d_out, nullptr, 4096*1024/4);
}